// Round 13
// baseline (135.524 us; speedup 1.0000x reference)
//
#include <hip/hip_runtime.h>
#include <stdint.h>

// C = binarize(X) @ binarize(W), exact via MX-fp4 (+-1) scaled MFMA.
// X: 8192x4096 f32, W: 4096x4096 f32, C: 8192x4096 f32.
// fp4 e2m1: +1.0 = 0x2, -1.0 = 0xA. Scale E8M0 127 = 1.0 (word 0x7F7F7F7F).
//
// R13 = R12 with pack_a4's GRID FIXED: each thread packs one 16B unit
// (32 elems), so grid = M*K/32/256 = 4096 blocks; R12 launched 1024 -> 3/4
// of A4p held 0xAA poison (nibble 0xA = -1) -> absmax 476. Design unchanged:
//   TILED SLOT-MAJOR format: A4p[panel 32][kt 32][slot 4][row 256] 16B units
//   (slot s of row r = k-elems [kt*128+s*32, +31], even k low nibble).
//   -> staging source LINEAR (coalesced, no swizzle)
//   -> LDS [slot][row]: 32x32 frag read = 32 lanes x 16B consecutive =
//      conflict-free; frag addrs = base VGPR + offset: immediates
//   -> 32x32x64 MFMA (9099 TF rate, half the instructions of 16x16x128;
//      operand pairing + C/D layout validated exact in R6)
//   Ring-4 LDS buffers + counted vmcnt skeleton from R10 (refcheck'd).
#define MDIM 8192
#define NDIM 4096
#define KDIM 4096
#define NT   (KDIM / 128)   // 32 K-tiles (BK = 128 elems = 64 B/row)
#define TILEB 16384         // one operand K-tile: 4 slots x 256 rows x 16 B

#define BM 256
#define BN 256
#define BUFSZ 32768         // A tile (16 KiB) + B tile (16 KiB)

typedef __attribute__((ext_vector_type(4)))  int   i32x4;
typedef __attribute__((ext_vector_type(8)))  int   i32x8;
typedef __attribute__((ext_vector_type(16))) float f32x16;

__device__ __forceinline__ void gload16(const void* g, void* l) {
    __builtin_amdgcn_global_load_lds(
        (const __attribute__((address_space(1))) void*)g,
        (__attribute__((address_space(3))) void*)l, 16, 0, 0);
}

__device__ __forceinline__ i32x8 pad8(i32x4 v) {
    i32x8 r;
    r[0] = v[0]; r[1] = v[1]; r[2] = v[2]; r[3] = v[3];
    r[4] = 0;    r[5] = 0;    r[6] = 0;    r[7] = 0;
    return r;
}

#define MFMA_FP4_32(a, b, c)                                                 \
    __builtin_amdgcn_mfma_scale_f32_32x32x64_f8f6f4(                          \
        (a), (b), (c), 4, 4, 0, 0x7F7F7F7F, 0, 0x7F7F7F7F)

// ---------------- pack X -> A4p[panel][kt][slot][row] ------------------------
// thread -> one 16B output unit (32 k-elems of one row); reads 128 B of X.
__global__ __launch_bounds__(256) void pack_a4_kernel(const float* __restrict__ X,
                                                      uint8_t* __restrict__ A4p) {
    int tg    = blockIdx.x * 256 + threadIdx.x;       // 0 .. 1M-1 (4096 blocks)
    int row   = tg & 255;
    int slot  = (tg >> 8) & 3;
    int kt    = (tg >> 10) & 31;
    int panel = tg >> 15;
    const float4* src = (const float4*)(X + (size_t)(panel * 256 + row) * KDIM
                                          + kt * 128 + slot * 32);
    uint32_t w[4];
#pragma unroll
    for (int q = 0; q < 4; ++q) {                     // 8 elems -> 1 uint
        float4 a = src[q * 2], b = src[q * 2 + 1];
        w[q] = (a.x >= 0.f ? 0x2u : 0xAu)        | ((a.y >= 0.f ? 0x2u : 0xAu) << 4)
             | ((a.z >= 0.f ? 0x2u : 0xAu) << 8) | ((a.w >= 0.f ? 0x2u : 0xAu) << 12)
             | ((b.x >= 0.f ? 0x2u : 0xAu) << 16)| ((b.y >= 0.f ? 0x2u : 0xAu) << 20)
             | ((b.z >= 0.f ? 0x2u : 0xAu) << 24)| ((b.w >= 0.f ? 0x2u : 0xAu) << 28);
    }
    ((uint4*)A4p)[tg] = make_uint4(w[0], w[1], w[2], w[3]);   // addr = tg*16
}

// ---------------- pack W -> B4p[panel][kt][slot][row_n] (transposed) ---------
// block = 64 n x 128 k; register transpose (8k x 4n patch/thread), LDS holds
// k-packed bytes P[n][kbyte] (stride 80), 1 b128 read/thread.
__global__ __launch_bounds__(256) void pack_b4t_kernel(const float* __restrict__ W,
                                                       uint8_t* __restrict__ B4p) {
    __shared__ uint8_t P[64 * 80];
    const int t  = threadIdx.x;
    const int n0 = blockIdx.x * 64;
    const int k0 = blockIdx.y * 128;                  // kt = blockIdx.y
    const int nt = t & 15, ks = t >> 4;               // 4-n group, 8-k slab
    uint32_t a0 = 0, a1 = 0, a2 = 0, a3 = 0;
#pragma unroll
    for (int j = 0; j < 8; ++j) {                     // byte j>>1, nibble j&1
        float4 v = *(const float4*)&W[(size_t)(k0 + ks * 8 + j) * NDIM + n0 + nt * 4];
        int sh = (j >> 1) * 8 + (j & 1) * 4;
        a0 |= (v.x >= 0.f ? 0x2u : 0xAu) << sh;
        a1 |= (v.y >= 0.f ? 0x2u : 0xAu) << sh;
        a2 |= (v.z >= 0.f ? 0x2u : 0xAu) << sh;
        a3 |= (v.w >= 0.f ? 0x2u : 0xAu) << sh;
    }
    *(uint32_t*)&P[(nt * 4 + 0) * 80 + ks * 4] = a0;
    *(uint32_t*)&P[(nt * 4 + 1) * 80 + ks * 4] = a1;
    *(uint32_t*)&P[(nt * 4 + 2) * 80 + ks * 4] = a2;
    *(uint32_t*)&P[(nt * 4 + 3) * 80 + ks * 4] = a3;
    __syncthreads();
    const int n = t >> 2, slot = t & 3;               // one 16B unit each
    uint4 val = *(const uint4*)&P[n * 80 + slot * 16];
    const int pn = (n0 + n) >> 8, rn = (n0 + n) & 255;
    size_t addr = ((((size_t)pn * 32 + blockIdx.y) * 4 + slot) * 256 + rn) * 16;
    *(uint4*)&B4p[addr] = val;
}

// ---------------- main: fp4 32x32x64 MFMA GEMM, ring-4 counted-vmcnt ---------
__global__ __launch_bounds__(512, 2) void binmm_fp4_kernel(const uint8_t* __restrict__ A4p,
                                                           const uint8_t* __restrict__ B4p,
                                                           float* __restrict__ C) {
    __shared__ uint8_t lds[4 * BUFSZ];                // 128 KiB

    const int tid = threadIdx.x, lane = tid & 63, wid = tid >> 6;
    const int wr = wid >> 2, wc = wid & 3;            // 2x4 waves; tile 128x64
    const int l31 = lane & 31, kh = lane >> 5;
    const int m0 = blockIdx.y * BM, n0 = blockIdx.x * BN;

    // staging: linear source (tiled global) -> linear LDS (legal gload form)
    const uint8_t* pA = A4p + (size_t)blockIdx.y * 32 * TILEB + tid * 16;
    const uint8_t* pB = B4p + (size_t)blockIdx.x * 32 * TILEB + tid * 16;

#define STAGE(bufOff, t) do {                                                  \
        gload16(pA + (t) * TILEB,        lds + (bufOff) + tid * 16);           \
        gload16(pA + (t) * TILEB + 8192, lds + (bufOff) + 8192  + tid * 16);   \
        gload16(pB + (t) * TILEB,        lds + (bufOff) + 16384 + tid * 16);   \
        gload16(pB + (t) * TILEB + 8192, lds + (bufOff) + 24576 + tid * 16);   \
    } while (0)

    // fragment bases: LDS [slot][row]: addr = slot*4096 + row*16 (+16384 for B)
    // frag (mf|nf, K-step s): base + {mf*512|nf*512} + s*8192  (kh in base)
    const int aBase = kh * 4096 + (wr * 128 + l31) * 16;
    const int bBase = 16384 + kh * 4096 + (wc * 64 + l31) * 16;

    f32x16 acc[4][2];
#pragma unroll
    for (int m = 0; m < 4; ++m)
#pragma unroll
        for (int n = 0; n < 2; ++n)
#pragma unroll
            for (int e = 0; e < 16; ++e) acc[m][n][e] = 0.f;

#define COMPUTE(bufOff) do {                                                   \
        const uint8_t* bp_ = lds + (bufOff);                                   \
        i32x8 bF[2][2];                                                        \
        _Pragma("unroll")                                                      \
        for (int nf = 0; nf < 2; ++nf)                                         \
            _Pragma("unroll")                                                  \
            for (int s = 0; s < 2; ++s)                                        \
                bF[nf][s] = pad8(*(const i32x4*)(bp_ + bBase + nf * 512 + s * 8192)); \
        __builtin_amdgcn_s_setprio(1);                                         \
        _Pragma("unroll")                                                      \
        for (int s = 0; s < 2; ++s)                                            \
            _Pragma("unroll")                                                  \
            for (int mf = 0; mf < 4; ++mf) {                                   \
                i32x8 a8 = pad8(*(const i32x4*)(bp_ + aBase + mf * 512 + s * 8192)); \
                acc[mf][0] = MFMA_FP4_32(a8, bF[0][s], acc[mf][0]);            \
                acc[mf][1] = MFMA_FP4_32(a8, bF[1][s], acc[mf][1]);            \
            }                                                                  \
        __builtin_amdgcn_s_setprio(0);                                         \
    } while (0)

#define SYNC(n) do {                                                           \
        __builtin_amdgcn_sched_barrier(0);                                     \
        asm volatile("s_waitcnt vmcnt(" #n ")" ::: "memory");                  \
        __builtin_amdgcn_s_barrier();                                          \
        __builtin_amdgcn_sched_barrier(0);                                     \
    } while (0)

    // prologue: stage tiles 0,1,2 (12 loads in flight), wait tile 0 (vmcnt 8)
    STAGE(0, 0);
    STAGE(BUFSZ, 1);
    STAGE(2 * BUFSZ, 2);
    SYNC(8);

    // steady state t=0..28: stage t+3, compute t, retire t+1's loads (vmcnt 8)
#pragma unroll 1
    for (int t = 0; t < NT - 3; ++t) {
        STAGE(((t + 3) & 3) * BUFSZ, t + 3);
        COMPUTE((t & 3) * BUFSZ);
        SYNC(8);
    }
    // tail: tiles 29,30,31 (bufs 1,2,3); counted drain 4 -> 0
    COMPUTE(1 * BUFSZ);
    SYNC(4);
    COMPUTE(2 * BUFSZ);
    SYNC(0);
    COMPUTE(3 * BUFSZ);

    // epilogue: C/D 32x32: col = lane&31, row = (reg&3) + 8*(reg>>2) + 4*kh
#pragma unroll
    for (int mf = 0; mf < 4; ++mf) {
#pragma unroll
        for (int nf = 0; nf < 2; ++nf) {
            size_t cc = (size_t)(n0 + wc * 64 + nf * 32 + l31);
            int rbase = m0 + wr * 128 + mf * 32 + 4 * kh;
#pragma unroll
            for (int reg = 0; reg < 16; ++reg) {
                int rr = (reg & 3) + 8 * (reg >> 2);
                C[(size_t)(rbase + rr) * NDIM + cc] = acc[mf][nf][reg];
            }
        }
    }
#undef STAGE
#undef COMPUTE
#undef SYNC
}

// =============================================================================
extern "C" void kernel_launch(void* const* d_in, const int* in_sizes, int n_in,
                              void* d_out, int out_size, void* d_ws, size_t ws_size,
                              hipStream_t stream) {
    const float* x = (const float*)d_in[0];   // [8192][4096]
    const float* w = (const float*)d_in[1];   // [4096][4096]
    float* out = (float*)d_out;               // [8192][4096]

    // workspace: A4p tiled (16 MiB) then B4p tiled (8 MiB)
    uint8_t* A4p = (uint8_t*)d_ws;
    uint8_t* B4p = (uint8_t*)d_ws + (size_t)MDIM * (KDIM / 2);

    // grid: one thread per 16B unit = M*K/32 units / 256 threads = 4096 blocks
    pack_a4_kernel<<<(int)((size_t)MDIM * KDIM / 32 / 256), 256, 0, stream>>>(x, A4p);
    pack_b4t_kernel<<<dim3(NDIM / 64, KDIM / 128), 256, 0, stream>>>(w, B4p);
    binmm_fp4_kernel<<<dim3(NDIM / BN, MDIM / BM), 512, 0, stream>>>(A4p, B4p, out);
}

// Round 14
// 135.356 us; speedup vs baseline: 1.0012x; 1.0012x over previous
//
#include <hip/hip_runtime.h>
#include <stdint.h>

// C = binarize(X) @ binarize(W), exact via MX-fp4 (+-1) scaled MFMA.
// X: 8192x4096 f32, W: 4096x4096 f32, C: 8192x4096 f32.
// fp4 e2m1: +1.0 = 0x2, -1.0 = 0xA. Scale E8M0 127 = 1.0 (word 0x7F7F7F7F).
//
// R14: 4 WAVES/SIMD. R13's plateau (82us, 5 structures at 82-89) decomposes
// as LDS(1152cyc) + MFMA(1133cyc) + sync(~800) run SERIALLY per K-tile: with
// 2 waves/SIMD in one lockstep block, reads and MFMA phase-align. Fix by
// occupancy: wave tile 64x64 (acc=64 AGPR, total regs <=128) x 16 waves
// (1024 thr) = 4 waves/SIMD -> TLP anti-phases the pipes (m114). Geometry,
// slot-major tiled format, ring-4 counted-vmcnt skeleton from R13 (refcheck'd)
// unchanged; 2 gloads/thread/tile -> SYNC(4). pack_a4 rewritten wave-coalesced
// (8KB contiguous per wave; R13's was 16KB-strided 128B chunks, ~+17us).
#define MDIM 8192
#define NDIM 4096
#define KDIM 4096
#define NT   (KDIM / 128)   // 32 K-tiles (BK = 128 elems = 64 B/row)
#define TILEB 16384         // one operand K-tile: 4 slots x 256 rows x 16 B

#define BM 256
#define BN 256
#define BUFSZ 32768         // A tile (16 KiB) + B tile (16 KiB)

typedef __attribute__((ext_vector_type(4)))  int   i32x4;
typedef __attribute__((ext_vector_type(8)))  int   i32x8;
typedef __attribute__((ext_vector_type(16))) float f32x16;

__device__ __forceinline__ void gload16(const void* g, void* l) {
    __builtin_amdgcn_global_load_lds(
        (const __attribute__((address_space(1))) void*)g,
        (__attribute__((address_space(3))) void*)l, 16, 0, 0);
}

__device__ __forceinline__ i32x8 pad8(i32x4 v) {
    i32x8 r;
    r[0] = v[0]; r[1] = v[1]; r[2] = v[2]; r[3] = v[3];
    r[4] = 0;    r[5] = 0;    r[6] = 0;    r[7] = 0;
    return r;
}

#define MFMA_FP4_32(a, b, c)                                                 \
    __builtin_amdgcn_mfma_scale_f32_32x32x64_f8f6f4(                          \
        (a), (b), (c), 4, 4, 0, 0x7F7F7F7F, 0, 0x7F7F7F7F)

// ---------------- pack X -> A4p[panel][kt][slot][row], wave-coalesced --------
// wave -> (row, half-K chunk): 64 lanes x 128B = 8KB contiguous read.
// lane packs 32 elems -> one 16B unit at (kt = chunk*16 + lane>>2, slot=lane&3).
__global__ __launch_bounds__(256) void pack_a4_kernel(const float* __restrict__ X,
                                                      uint8_t* __restrict__ A4p) {
    int gw   = blockIdx.x * 4 + (threadIdx.x >> 6);   // global wave id
    int lane = threadIdx.x & 63;
    int row  = gw >> 1, chunk = gw & 1;
    const float4* src = (const float4*)(X + (size_t)row * KDIM
                                          + chunk * 2048 + lane * 32);
    uint32_t w[4];
#pragma unroll
    for (int q = 0; q < 4; ++q) {                     // 8 elems -> 1 uint
        float4 a = src[q * 2], b = src[q * 2 + 1];
        w[q] = (a.x >= 0.f ? 0x2u : 0xAu)        | ((a.y >= 0.f ? 0x2u : 0xAu) << 4)
             | ((a.z >= 0.f ? 0x2u : 0xAu) << 8) | ((a.w >= 0.f ? 0x2u : 0xAu) << 12)
             | ((b.x >= 0.f ? 0x2u : 0xAu) << 16)| ((b.y >= 0.f ? 0x2u : 0xAu) << 20)
             | ((b.z >= 0.f ? 0x2u : 0xAu) << 24)| ((b.w >= 0.f ? 0x2u : 0xAu) << 28);
    }
    int kt = chunk * 16 + (lane >> 2), slot = lane & 3;
    size_t unit = ((((size_t)(row >> 8) * 32 + kt) * 4 + slot) * 256) + (row & 255);
    ((uint4*)A4p)[unit] = make_uint4(w[0], w[1], w[2], w[3]);
}

// ---------------- pack W -> B4p[panel][kt][slot][row_n] (transposed) ---------
// (unchanged from R13, refcheck'd) register transpose 8k x 4n patch/thread.
__global__ __launch_bounds__(256) void pack_b4t_kernel(const float* __restrict__ W,
                                                       uint8_t* __restrict__ B4p) {
    __shared__ uint8_t P[64 * 80];
    const int t  = threadIdx.x;
    const int n0 = blockIdx.x * 64;
    const int k0 = blockIdx.y * 128;                  // kt = blockIdx.y
    const int nt = t & 15, ks = t >> 4;               // 4-n group, 8-k slab
    uint32_t a0 = 0, a1 = 0, a2 = 0, a3 = 0;
#pragma unroll
    for (int j = 0; j < 8; ++j) {                     // byte j>>1, nibble j&1
        float4 v = *(const float4*)&W[(size_t)(k0 + ks * 8 + j) * NDIM + n0 + nt * 4];
        int sh = (j >> 1) * 8 + (j & 1) * 4;
        a0 |= (v.x >= 0.f ? 0x2u : 0xAu) << sh;
        a1 |= (v.y >= 0.f ? 0x2u : 0xAu) << sh;
        a2 |= (v.z >= 0.f ? 0x2u : 0xAu) << sh;
        a3 |= (v.w >= 0.f ? 0x2u : 0xAu) << sh;
    }
    *(uint32_t*)&P[(nt * 4 + 0) * 80 + ks * 4] = a0;
    *(uint32_t*)&P[(nt * 4 + 1) * 80 + ks * 4] = a1;
    *(uint32_t*)&P[(nt * 4 + 2) * 80 + ks * 4] = a2;
    *(uint32_t*)&P[(nt * 4 + 3) * 80 + ks * 4] = a3;
    __syncthreads();
    const int n = t >> 2, slot = t & 3;               // one 16B unit each
    uint4 val = *(const uint4*)&P[n * 80 + slot * 16];
    const int pn = (n0 + n) >> 8, rn = (n0 + n) & 255;
    size_t addr = ((((size_t)pn * 32 + blockIdx.y) * 4 + slot) * 256 + rn) * 16;
    *(uint4*)&B4p[addr] = val;
}

// ---------------- main: fp4 32x32x64, 16 waves, 4 waves/SIMD -----------------
__global__ __launch_bounds__(1024, 4) void binmm_fp4_kernel(const uint8_t* __restrict__ A4p,
                                                            const uint8_t* __restrict__ B4p,
                                                            float* __restrict__ C) {
    __shared__ uint8_t lds[4 * BUFSZ];                // 128 KiB

    const int tid = threadIdx.x, lane = tid & 63, wid = tid >> 6;
    const int wr = wid >> 2, wc = wid & 3;            // 4x4 waves; tile 64x64
    const int l31 = lane & 31, kh = lane >> 5;
    const int m0 = blockIdx.y * BM, n0 = blockIdx.x * BN;

    // staging: linear source -> linear LDS; 1024 thr x 16B = one 16KiB operand
    // tile per gload (2 gloads/thread/K-tile).
    const uint8_t* pA = A4p + (size_t)blockIdx.y * 32 * TILEB + tid * 16;
    const uint8_t* pB = B4p + (size_t)blockIdx.x * 32 * TILEB + tid * 16;

#define STAGE(bufOff, t) do {                                                  \
        gload16(pA + (t) * TILEB, lds + (bufOff) + tid * 16);                  \
        gload16(pB + (t) * TILEB, lds + (bufOff) + 16384 + tid * 16);          \
    } while (0)

    // fragment bases: LDS [slot][row], addr = slot*4096 + row*16 (+16384 B)
    const int aBase = kh * 4096 + (wr * 64 + l31) * 16;
    const int bBase = 16384 + kh * 4096 + (wc * 64 + l31) * 16;

    f32x16 acc[2][2];
#pragma unroll
    for (int m = 0; m < 2; ++m)
#pragma unroll
        for (int n = 0; n < 2; ++n)
#pragma unroll
            for (int e = 0; e < 16; ++e) acc[m][n][e] = 0.f;

#define COMPUTE(bufOff) do {                                                   \
        const uint8_t* bp_ = lds + (bufOff);                                   \
        _Pragma("unroll")                                                      \
        for (int s = 0; s < 2; ++s) {                                          \
            i32x4 a0 = *(const i32x4*)(bp_ + aBase + s * 8192);                \
            i32x4 a1 = *(const i32x4*)(bp_ + aBase + 512 + s * 8192);          \
            i32x4 b0 = *(const i32x4*)(bp_ + bBase + s * 8192);                \
            i32x4 b1 = *(const i32x4*)(bp_ + bBase + 512 + s * 8192);          \
            __builtin_amdgcn_s_setprio(1);                                     \
            acc[0][0] = MFMA_FP4_32(pad8(a0), pad8(b0), acc[0][0]);            \
            acc[0][1] = MFMA_FP4_32(pad8(a0), pad8(b1), acc[0][1]);            \
            acc[1][0] = MFMA_FP4_32(pad8(a1), pad8(b0), acc[1][0]);            \
            acc[1][1] = MFMA_FP4_32(pad8(a1), pad8(b1), acc[1][1]);            \
            __builtin_amdgcn_s_setprio(0);                                     \
        }                                                                      \
    } while (0)

#define SYNC(n) do {                                                           \
        __builtin_amdgcn_sched_barrier(0);                                     \
        asm volatile("s_waitcnt vmcnt(" #n ")" ::: "memory");                  \
        __builtin_amdgcn_s_barrier();                                          \
        __builtin_amdgcn_sched_barrier(0);                                     \
    } while (0)

    // prologue: stage tiles 0,1,2 (6 loads in flight), wait tile 0 (vmcnt 4)
    STAGE(0, 0);
    STAGE(BUFSZ, 1);
    STAGE(2 * BUFSZ, 2);
    SYNC(4);

    // steady state t=0..28: stage t+3, compute t, retire t+1's loads (vmcnt 4)
#pragma unroll 1
    for (int t = 0; t < NT - 3; ++t) {
        STAGE(((t + 3) & 3) * BUFSZ, t + 3);
        COMPUTE((t & 3) * BUFSZ);
        SYNC(4);
    }
    // tail: tiles 29,30,31 (bufs 1,2,3); counted drain 2 -> 0
    COMPUTE(1 * BUFSZ);
    SYNC(2);
    COMPUTE(2 * BUFSZ);
    SYNC(0);
    COMPUTE(3 * BUFSZ);

    // epilogue: C/D 32x32: col = lane&31, row = (reg&3) + 8*(reg>>2) + 4*kh
#pragma unroll
    for (int mf = 0; mf < 2; ++mf) {
#pragma unroll
        for (int nf = 0; nf < 2; ++nf) {
            size_t cc = (size_t)(n0 + wc * 64 + nf * 32 + l31);
            int rbase = m0 + wr * 64 + mf * 32 + 4 * kh;
#pragma unroll
            for (int reg = 0; reg < 16; ++reg) {
                int rr = (reg & 3) + 8 * (reg >> 2);
                C[(size_t)(rbase + rr) * NDIM + cc] = acc[mf][nf][reg];
            }
        }
    }
#undef STAGE
#undef COMPUTE
#undef SYNC
}

// =============================================================================
extern "C" void kernel_launch(void* const* d_in, const int* in_sizes, int n_in,
                              void* d_out, int out_size, void* d_ws, size_t ws_size,
                              hipStream_t stream) {
    const float* x = (const float*)d_in[0];   // [8192][4096]
    const float* w = (const float*)d_in[1];   // [4096][4096]
    float* out = (float*)d_out;               // [8192][4096]

    // workspace: A4p tiled (16 MiB) then B4p tiled (8 MiB)
    uint8_t* A4p = (uint8_t*)d_ws;
    uint8_t* B4p = (uint8_t*)d_ws + (size_t)MDIM * (KDIM / 2);

    // pack_a4: one wave per (row, half-K) -> 8192*2 waves / 4 per block
    pack_a4_kernel<<<MDIM * 2 / 4, 256, 0, stream>>>(x, A4p);
    pack_b4t_kernel<<<dim3(NDIM / 64, KDIM / 128), 256, 0, stream>>>(w, B4p);
    binmm_fp4_kernel<<<dim3(NDIM / BN, MDIM / BM), 1024, 0, stream>>>(A4p, B4p, out);
}